// Round 6
// baseline (1803.697 us; speedup 1.0000x reference)
//
#include <hip/hip_runtime.h>

// GPT forward, MI355X. f32 inputs; bf16 MFMA GEMMs with f32 accum;
// LN/softmax/residual kept in f32. MFMA flash attention.
// GEMM "pipeline-4": BK=32, 4-deep circular LDS buffers, counted
// s_waitcnt vmcnt(8) (never 0 mid-loop), raw s_barrier (1/K-tile),
// global_load_lds width-16, XOR-swizzled LDS (slot ^= (row>>1)&3).

#define T_SEQ 1024
#define E_DIM 1024
#define H_NUM 16
#define D_HEAD 64
#define L_NUM 6
#define FF_DIM 4096
#define B_NUM 2
#define M_ROWS 2048   // B*T

using bf16x8 = __attribute__((ext_vector_type(8))) __bf16;
using f32x4  = __attribute__((ext_vector_type(4))) float;

__device__ __forceinline__ unsigned short f2bf(float f) {
  unsigned int u = __float_as_uint(f);
  u += 0x7fffu + ((u >> 16) & 1u);   // RNE
  return (unsigned short)(u >> 16);
}

// async global->LDS, 16B per lane. LDS dest is wave-uniform (HW adds lane*16).
__device__ __forceinline__ void gload_lds16(const void* g, void* l) {
  __builtin_amdgcn_global_load_lds(
      (const __attribute__((address_space(1))) unsigned int*)g,
      (__attribute__((address_space(3))) unsigned int*)l, 16, 0, 0);
}

// ---------------- embed: x[b*T+t][e] = tok_w[idx][e] + pos[t][e] ----------
__global__ __launch_bounds__(256) void embed_k(const int* __restrict__ idx,
                                               const float* __restrict__ tok_w,
                                               const float* __restrict__ pos,
                                               float* __restrict__ x) {
  const int i = blockIdx.x;            // 0..2047
  const int t = i & (T_SEQ - 1);
  const int tok = idx[i];
  const float4 a = ((const float4*)(tok_w + (size_t)tok * E_DIM))[threadIdx.x];
  const float4 p = ((const float4*)(pos + (size_t)t * E_DIM))[threadIdx.x];
  float4 o;
  o.x = a.x + p.x; o.y = a.y + p.y; o.z = a.z + p.z; o.w = a.w + p.w;
  ((float4*)(x + (size_t)i * E_DIM))[threadIdx.x] = o;
}

// ---------------- layernorm: f32 in -> bf16 out ---------------------------
__global__ __launch_bounds__(256) void ln_k(const float* __restrict__ x,
                                            const float* __restrict__ s,
                                            const float* __restrict__ b,
                                            unsigned short* __restrict__ out) {
  const int row = blockIdx.x, tid = threadIdx.x;
  const float4 v = ((const float4*)(x + (size_t)row * E_DIM))[tid];
  float sum = v.x + v.y + v.z + v.w;
  float sq  = v.x * v.x + v.y * v.y + v.z * v.z + v.w * v.w;
  #pragma unroll
  for (int off = 32; off; off >>= 1) {
    sum += __shfl_down(sum, off);
    sq  += __shfl_down(sq, off);
  }
  __shared__ float sm[10];
  const int wave = tid >> 6, lane = tid & 63;
  if (lane == 0) { sm[wave] = sum; sm[4 + wave] = sq; }
  __syncthreads();
  if (tid == 0) {
    const float ts = sm[0] + sm[1] + sm[2] + sm[3];
    const float tq = sm[4] + sm[5] + sm[6] + sm[7];
    const float mean = ts * (1.0f / E_DIM);
    const float var = tq * (1.0f / E_DIM) - mean * mean;
    sm[8] = mean;
    sm[9] = 1.0f / sqrtf(var + 1e-5f);
  }
  __syncthreads();
  const float mean = sm[8], inv = sm[9];
  const float4 sv = ((const float4*)s)[tid];
  const float4 bv = ((const float4*)b)[tid];
  ushort4 o;
  o.x = f2bf((v.x - mean) * inv * sv.x + bv.x);
  o.y = f2bf((v.y - mean) * inv * sv.y + bv.y);
  o.z = f2bf((v.z - mean) * inv * sv.z + bv.z);
  o.w = f2bf((v.w - mean) * inv * sv.w + bv.w);
  *(ushort4*)(out + (size_t)row * E_DIM + (tid << 2)) = o;
}

// ------- batched transpose + f32->bf16: WT[n][k] = W[k][n], z = layer -----
__global__ __launch_bounds__(256) void transpose_b(const float* __restrict__ W,
                                                   unsigned short* __restrict__ WT,
                                                   int K, int N,
                                                   size_t Wstride, size_t WTstride) {
  __shared__ float tile[32][33];
  const int z = blockIdx.z;
  W  += (size_t)z * Wstride;
  WT += (size_t)z * WTstride;
  const int n0 = blockIdx.x << 5, k0 = blockIdx.y << 5;
  const int tx = threadIdx.x & 31, ty = threadIdx.x >> 5;
  #pragma unroll
  for (int i = ty; i < 32; i += 8)
    tile[i][tx] = W[(size_t)(k0 + i) * N + n0 + tx];
  __syncthreads();
  #pragma unroll
  for (int i = ty; i < 32; i += 8)
    WT[(size_t)(n0 + i) * K + k0 + tx] = f2bf(tile[tx][i]);
}

// ---------------- bf16 MFMA GEMM: C[M,N] = A[M,K] @ WT[N,K]^T -------------
// pipeline-4: BK=32, 4 circular LDS buffers, counted vmcnt, raw s_barrier.
// Wave grid WM x WN; per-wave tile (BM/WM) x (BN/WN); 16x16x32 frags.
template<int BM, int BN, int NW, int WM, int WN,
         bool RELU, bool BIAS, bool RES, bool OBF16>
__global__ __launch_bounds__(NW * 64) void gemm_p(
    const unsigned short* __restrict__ A, const unsigned short* __restrict__ WT,
    const float* __restrict__ bias, const float* __restrict__ res,
    void* __restrict__ Cout, int ldc, int K) {
  constexpr int BK = 32;                    // 64 B rows = 4 slots of 16 B
  constexpr int NT = NW * 64;
  constexpr int WTM = BM / WM, WTN = BN / WN;
  constexpr int MR = WTM / 16, NR = WTN / 16;
  constexpr int AJ = 4 * BM / NT;           // A 1KB-chunk issues per thread
  constexpr int BJ = 4 * BN / NT;           // B 1KB-chunk issues per thread
  constexpr int ATILE = BM * BK * 2;        // bytes per A tile
  constexpr int BTILE = BN * BK * 2;
  __shared__ __align__(16) unsigned short AsB[4 * BM * BK];
  __shared__ __align__(16) unsigned short BsB[4 * BN * BK];
  const int tid = threadIdx.x;
  const int row0 = blockIdx.x * BM, col0 = blockIdx.y * BN;
  const int wave = tid >> 6, lane = tid & 63;
  const int wm = (wave / WN) * WTM, wn = (wave % WN) * WTN;
  const int lr = lane & 15, lg = lane >> 4;       // frag row / k-slot (0..3)
  const int ric = lane >> 2, sslot = lane & 3;    // staging row-in-chunk / slot

  auto stage = [&](int b, int k0) {
    #pragma unroll
    for (int j = 0; j < AJ; ++j) {
      const int c = wave + NW * j;          // 1KB chunk (16 rows)
      const int row = c * 16 + ric;
      const int sp = sslot ^ ((row >> 1) & 3);    // inverse-swizzled source slot
      gload_lds16(A + (size_t)(row0 + row) * K + k0 + sp * 8,
                  (char*)AsB + b * ATILE + c * 1024);
    }
    #pragma unroll
    for (int j = 0; j < BJ; ++j) {
      const int c = wave + NW * j;
      const int row = c * 16 + ric;
      const int sp = sslot ^ ((row >> 1) & 3);
      gload_lds16(WT + (size_t)(col0 + row) * K + k0 + sp * 8,
                  (char*)BsB + b * BTILE + c * 1024);
    }
  };

  f32x4 acc[MR][NR] = {};
  const int nt = K / BK;                    // >= 32 for all our GEMMs
  stage(0, 0); stage(1, BK); stage(2, 2 * BK);    // 12 loads in flight

  for (int t = 0; t < nt; ++t) {
    // drain ONLY tile t's 4 loads; t+1/t+2 stay in flight (never vmcnt 0)
    if (t + 3 < nt)      asm volatile("s_waitcnt vmcnt(8)" ::: "memory");
    else if (t + 2 < nt) asm volatile("s_waitcnt vmcnt(4)" ::: "memory");
    else                 asm volatile("s_waitcnt vmcnt(0)" ::: "memory");
    __builtin_amdgcn_s_barrier();           // all waves: tile t ready, t-1 reads done
    asm volatile("" ::: "memory");
    if (t + 3 < nt) stage((t + 3) & 3, (t + 3) * BK);  // into buf freed by t-1

    const char* Ab = (const char*)AsB + (t & 3) * ATILE;
    const char* Bb = (const char*)BsB + (t & 3) * BTILE;
    bf16x8 bfr[NR];
    #pragma unroll
    for (int n = 0; n < NR; ++n) {
      const int r = wn + n * 16 + lr;
      const int s = lg ^ ((r >> 1) & 3);
      bfr[n] = *(const bf16x8*)(Bb + r * 64 + s * 16);
    }
    #pragma unroll
    for (int m = 0; m < MR; ++m) {
      const int r = wm + m * 16 + lr;
      const int s = lg ^ ((r >> 1) & 3);
      const bf16x8 af = *(const bf16x8*)(Ab + r * 64 + s * 16);
      __builtin_amdgcn_s_setprio(1);
      #pragma unroll
      for (int n = 0; n < NR; ++n)
        acc[m][n] = __builtin_amdgcn_mfma_f32_16x16x32_bf16(af, bfr[n], acc[m][n], 0, 0, 0);
      __builtin_amdgcn_s_setprio(0);
    }
  }
  float* Cf = (float*)Cout;
  unsigned short* Cb = (unsigned short*)Cout;
  #pragma unroll
  for (int m = 0; m < MR; ++m) {
    #pragma unroll
    for (int n = 0; n < NR; ++n) {
      const int col = col0 + wn + n * 16 + lr;
      const float bv = BIAS ? bias[col] : 0.0f;
      #pragma unroll
      for (int r = 0; r < 4; ++r) {
        const int row = row0 + wm + m * 16 + lg * 4 + r;
        float val = acc[m][n][r] + bv;
        if (RELU) val = fmaxf(val, 0.0f);
        if (RES)  val += res[(size_t)row * ldc + col];
        if (OBF16) Cb[(size_t)row * ldc + col] = f2bf(val);
        else       Cf[(size_t)row * ldc + col] = val;
      }
    }
  }
}

// ---------------- MFMA flash attention ------------------------------------
// qkv bf16 [2048][3072] (q|k|v), ob bf16 [2048][1024].
// Block = (q-tile 64 rows, head, batch); 4 waves, wave owns 16 q rows.
#define QBLK 64
#define KBLK 64
__global__ __launch_bounds__(256) void fattn_k(const unsigned short* __restrict__ qkv,
                                               unsigned short* __restrict__ ob) {
  const int qt = blockIdx.x, h = blockIdx.y, b = blockIdx.z;
  const int tid = threadIdx.x;
  const int wave = tid >> 6, lane = tid & 63;
  const int lr = lane & 15, lg = lane >> 4;      // lg = 0..3
  const int q0 = qt * QBLK;

  __shared__ __align__(16) unsigned short Qs[QBLK][72];
  __shared__ __align__(16) unsigned short Ks[KBLK][72];
  __shared__ __align__(16) unsigned short Vt[D_HEAD][72];   // transposed V
  __shared__ __align__(16) unsigned short Ps[QBLK][72];

  const size_t base = (size_t)b * T_SEQ * 3072 + (size_t)h * 64;
  const int srow = tid >> 3, scol = (tid & 7) << 3;

  // stage Q tile
  #pragma unroll
  for (int it = 0; it < 2; ++it) {
    const int row = srow + it * 32;
    *(uint4*)&Qs[row][scol] =
        *(const uint4*)(qkv + base + (size_t)(q0 + row) * 3072 + scol);
  }
  __syncthreads();
  bf16x8 qf[2];
  #pragma unroll
  for (int ks = 0; ks < 2; ++ks)
    qf[ks] = *(const bf16x8*)&Qs[wave * 16 + lr][ks * 32 + lg * 8];

  f32x4 acc_o[4] = {};
  float mrow[4], lrow[4];
  #pragma unroll
  for (int r = 0; r < 4; ++r) { mrow[r] = -3.0e38f; lrow[r] = 0.f; }

  const int ntile = qt + 1;
  for (int kt = 0; kt < ntile; ++kt) {
    const int s0 = kt * KBLK;
    __syncthreads();   // previous iteration done with Ks/Vt/Ps
    #pragma unroll
    for (int it = 0; it < 2; ++it) {
      const int row = srow + it * 32;
      *(uint4*)&Ks[row][scol] =
          *(const uint4*)(qkv + base + 1024 + (size_t)(s0 + row) * 3072 + scol);
      uint4 v4 = *(const uint4*)(qkv + base + 2048 + (size_t)(s0 + row) * 3072 + scol);
      const unsigned short* vs = (const unsigned short*)&v4;
      #pragma unroll
      for (int j = 0; j < 8; ++j) Vt[scol + j][row] = vs[j];
    }
    __syncthreads();

    // S = Q K^T (per wave: 16 q rows x 64 s cols)
    f32x4 sacc[4] = {};
    #pragma unroll
    for (int ks = 0; ks < 2; ++ks) {
      #pragma unroll
      for (int nf = 0; nf < 4; ++nf) {
        bf16x8 kf = *(const bf16x8*)&Ks[nf * 16 + lr][ks * 32 + lg * 8];
        sacc[nf] = __builtin_amdgcn_mfma_f32_16x16x32_bf16(qf[ks], kf, sacc[nf], 0, 0, 0);
      }
    }
    float sv[4][4];
    #pragma unroll
    for (int nf = 0; nf < 4; ++nf)
      #pragma unroll
      for (int r = 0; r < 4; ++r) sv[nf][r] = sacc[nf][r] * 0.125f;
    if (kt == ntile - 1) {         // diagonal tile: causal mask
      #pragma unroll
      for (int nf = 0; nf < 4; ++nf) {
        const int s = s0 + nf * 16 + lr;
        #pragma unroll
        for (int r = 0; r < 4; ++r) {
          const int q = q0 + wave * 16 + lg * 4 + r;
          if (s > q) sv[nf][r] = -3.0e38f;
        }
      }
    }
    // online softmax per q-row (rows live in 16-lane groups)
    float p[4][4];
    #pragma unroll
    for (int r = 0; r < 4; ++r) {
      float mx = fmaxf(fmaxf(sv[0][r], sv[1][r]), fmaxf(sv[2][r], sv[3][r]));
      #pragma unroll
      for (int off = 1; off < 16; off <<= 1) mx = fmaxf(mx, __shfl_xor(mx, off));
      const float mnew = fmaxf(mrow[r], mx);
      const float alpha = __expf(mrow[r] - mnew);
      mrow[r] = mnew;
      float sum = 0.f;
      #pragma unroll
      for (int nf = 0; nf < 4; ++nf) {
        p[nf][r] = __expf(sv[nf][r] - mnew);
        sum += p[nf][r];
      }
      #pragma unroll
      for (int off = 1; off < 16; off <<= 1) sum += __shfl_xor(sum, off);
      lrow[r] = lrow[r] * alpha + sum;
      #pragma unroll
      for (int df = 0; df < 4; ++df) acc_o[df][r] *= alpha;
    }
    // stage P (bf16) for the PV MFMA
    #pragma unroll
    for (int nf = 0; nf < 4; ++nf)
      #pragma unroll
      for (int r = 0; r < 4; ++r)
        Ps[wave * 16 + lg * 4 + r][nf * 16 + lr] = f2bf(p[nf][r]);
    __syncthreads();
    // O += P V
    #pragma unroll
    for (int ks = 0; ks < 2; ++ks) {
      bf16x8 pa = *(const bf16x8*)&Ps[wave * 16 + lr][ks * 32 + lg * 8];
      #pragma unroll
      for (int df = 0; df < 4; ++df) {
        bf16x8 vf = *(const bf16x8*)&Vt[df * 16 + lr][ks * 32 + lg * 8];
        acc_o[df] = __builtin_amdgcn_mfma_f32_16x16x32_bf16(pa, vf, acc_o[df], 0, 0, 0);
      }
    }
  }
  // epilogue: O / l -> ob
  #pragma unroll
  for (int r = 0; r < 4; ++r) {
    const float inv = 1.0f / lrow[r];
    const int row = q0 + wave * 16 + lg * 4 + r;
    #pragma unroll
    for (int df = 0; df < 4; ++df)
      ob[((size_t)b * T_SEQ + row) * E_DIM + h * 64 + df * 16 + lr] =
          f2bf(acc_o[df][r] * inv);
  }
}

extern "C" void kernel_launch(void* const* d_in, const int* in_sizes, int n_in,
                              void* d_out, int out_size, void* d_ws, size_t ws_size,
                              hipStream_t stream) {
  (void)in_sizes; (void)n_in; (void)out_size; (void)ws_size;
  const int*   idx    = (const int*)d_in[0];
  const float* tok_w  = (const float*)d_in[1];
  const float* pos    = (const float*)d_in[2];
  const float* ln1_s  = (const float*)d_in[3];
  const float* ln1_b  = (const float*)d_in[4];
  const float* wq     = (const float*)d_in[5];
  const float* wk     = (const float*)d_in[6];
  const float* wv     = (const float*)d_in[7];
  const float* wo     = (const float*)d_in[8];
  const float* bo     = (const float*)d_in[9];
  const float* ln2_s  = (const float*)d_in[10];
  const float* ln2_b  = (const float*)d_in[11];
  const float* w1     = (const float*)d_in[12];
  const float* b1     = (const float*)d_in[13];
  const float* w2     = (const float*)d_in[14];
  const float* b2     = (const float*)d_in[15];
  const float* lnf_s  = (const float*)d_in[16];
  const float* lnf_b  = (const float*)d_in[17];
  const float* head_w = (const float*)d_in[18];
  const float* head_b = (const float*)d_in[19];
  float* out = (float*)d_out;

  char* p = (char*)d_ws;
  float* x            = (float*)p;          p += (size_t)M_ROWS * E_DIM * 4;       // 8 MB
  unsigned short* qkvb= (unsigned short*)p; p += (size_t)M_ROWS * 3072 * 2;        // 12.6 MB
  unsigned short* h   = (unsigned short*)p; p += (size_t)M_ROWS * E_DIM * 2;       // 4 MB
  unsigned short* obuf= (unsigned short*)p; p += (size_t)M_ROWS * E_DIM * 2;       // 4 MB
  unsigned short* ff  = (unsigned short*)p; p += (size_t)M_ROWS * FF_DIM * 2;      // 16 MB
  unsigned short* wtqkv=(unsigned short*)p; p += (size_t)L_NUM * 3072 * E_DIM * 2; // 37.7 MB
  unsigned short* wto = (unsigned short*)p; p += (size_t)L_NUM * E_DIM * E_DIM * 2;// 12.6 MB
  unsigned short* wt1 = (unsigned short*)p; p += (size_t)L_NUM * FF_DIM * E_DIM * 2;// 50.3 MB
  unsigned short* wt2 = (unsigned short*)p; p += (size_t)L_NUM * E_DIM * FF_DIM * 2;// 50.3 MB
  unsigned short* wth = (unsigned short*)p; p += (size_t)32000 * E_DIM * 2;        // 65.5 MB

  // ---- all weight transposes up front (batched over layers) ----
  transpose_b<<<dim3(32, 32, L_NUM), 256, 0, stream>>>(
      wq, wtqkv,           E_DIM, E_DIM, (size_t)E_DIM * E_DIM, (size_t)3072 * E_DIM);
  transpose_b<<<dim3(32, 32, L_NUM), 256, 0, stream>>>(
      wk, wtqkv + 1048576, E_DIM, E_DIM, (size_t)E_DIM * E_DIM, (size_t)3072 * E_DIM);
  transpose_b<<<dim3(32, 32, L_NUM), 256, 0, stream>>>(
      wv, wtqkv + 2097152, E_DIM, E_DIM, (size_t)E_DIM * E_DIM, (size_t)3072 * E_DIM);
  transpose_b<<<dim3(32, 32, L_NUM), 256, 0, stream>>>(
      wo, wto, E_DIM, E_DIM, (size_t)E_DIM * E_DIM, (size_t)E_DIM * E_DIM);
  transpose_b<<<dim3(128, 32, L_NUM), 256, 0, stream>>>(
      w1, wt1, E_DIM, FF_DIM, (size_t)E_DIM * FF_DIM, (size_t)FF_DIM * E_DIM);
  transpose_b<<<dim3(32, 128, L_NUM), 256, 0, stream>>>(
      w2, wt2, FF_DIM, E_DIM, (size_t)E_DIM * FF_DIM, (size_t)E_DIM * FF_DIM);
  transpose_b<<<dim3(1000, 32, 1), 256, 0, stream>>>(
      head_w, wth, E_DIM, 32000, 0, 0);

  embed_k<<<M_ROWS, 256, 0, stream>>>(idx, tok_w, pos, x);

  for (int l = 0; l < L_NUM; ++l) {
    // ---- LN1 ----
    ln_k<<<M_ROWS, 256, 0, stream>>>(x, ln1_s + l * E_DIM, ln1_b + l * E_DIM, h);
    // ---- QKV (fused, N = 3072, bf16 out): 128x128, 384 blocks ----
    gemm_p<128, 128, 4, 2, 2, false, false, false, true>
        <<<dim3(16, 24), 256, 0, stream>>>(
        h, wtqkv + (size_t)l * 3072 * E_DIM, nullptr, nullptr, qkvb, 3072, E_DIM);
    // ---- flash attention ----
    fattn_k<<<dim3(T_SEQ / QBLK, H_NUM, B_NUM), 256, 0, stream>>>(qkvb, obuf);
    // ---- out-proj + bias + residual into x: 64x128, 256 blocks ----
    gemm_p<64, 128, 4, 1, 4, false, true, true, false>
        <<<dim3(32, 8), 256, 0, stream>>>(
        obuf, wto + (size_t)l * E_DIM * E_DIM, bo + l * E_DIM, x, x, E_DIM, E_DIM);
    // ---- LN2 ----
    ln_k<<<M_ROWS, 256, 0, stream>>>(x, ln2_s + l * E_DIM, ln2_b + l * E_DIM, h);
    // ---- MLP up + ReLU (bf16 out): 128x128, 512 blocks ----
    gemm_p<128, 128, 4, 2, 2, true, true, false, true>
        <<<dim3(16, 32), 256, 0, stream>>>(
        h, wt1 + (size_t)l * FF_DIM * E_DIM, b1 + l * FF_DIM, nullptr, ff, FF_DIM, E_DIM);
    // ---- MLP down + bias + residual into x: 64x128, K=4096 ----
    gemm_p<64, 128, 4, 1, 4, false, true, true, false>
        <<<dim3(32, 8), 256, 0, stream>>>(
        ff, wt2 + (size_t)l * E_DIM * FF_DIM, b2 + l * E_DIM, x, x, E_DIM, FF_DIM);
  }

  // ---- final LN + head: 256x256, 8 waves, grid (8, 125) m-fastest ----
  ln_k<<<M_ROWS, 256, 0, stream>>>(x, lnf_s, lnf_b, h);
  gemm_p<256, 256, 8, 2, 4, false, true, false, false>
      <<<dim3(8, 125), 512, 0, stream>>>(
      h, wth, head_b, nullptr, out, 32000, E_DIM);
}

// Round 7
// 1593.905 us; speedup vs baseline: 1.1316x; 1.1316x over previous
//
#include <hip/hip_runtime.h>

// GPT forward, MI355X. f32 inputs; bf16 MFMA GEMMs with f32 accum;
// LN/softmax/residual kept in f32. MFMA flash attention.
// Layer GEMMs: R4 2-phase dbuf BK=64 (best measured). Head GEMM: 8-phase
// 256x256 8-wave template, counted vmcnt(4), quadrant-half consumption,
// XCD-swizzled grid. XOR-swizzled LDS everywhere (0 conflicts measured).

#define T_SEQ 1024
#define E_DIM 1024
#define H_NUM 16
#define D_HEAD 64
#define L_NUM 6
#define FF_DIM 4096
#define B_NUM 2
#define M_ROWS 2048   // B*T

using bf16x8 = __attribute__((ext_vector_type(8))) __bf16;
using f32x4  = __attribute__((ext_vector_type(4))) float;

__device__ __forceinline__ unsigned short f2bf(float f) {
  unsigned int u = __float_as_uint(f);
  u += 0x7fffu + ((u >> 16) & 1u);   // RNE
  return (unsigned short)(u >> 16);
}

// async global->LDS, 16B per lane. LDS dest is wave-uniform (HW adds lane*16).
__device__ __forceinline__ void gload_lds16(const void* g, void* l) {
  __builtin_amdgcn_global_load_lds(
      (const __attribute__((address_space(1))) unsigned int*)g,
      (__attribute__((address_space(3))) unsigned int*)l, 16, 0, 0);
}

// ---------------- embed ---------------------------------------------------
__global__ __launch_bounds__(256) void embed_k(const int* __restrict__ idx,
                                               const float* __restrict__ tok_w,
                                               const float* __restrict__ pos,
                                               float* __restrict__ x) {
  const int i = blockIdx.x;
  const int t = i & (T_SEQ - 1);
  const int tok = idx[i];
  const float4 a = ((const float4*)(tok_w + (size_t)tok * E_DIM))[threadIdx.x];
  const float4 p = ((const float4*)(pos + (size_t)t * E_DIM))[threadIdx.x];
  float4 o;
  o.x = a.x + p.x; o.y = a.y + p.y; o.z = a.z + p.z; o.w = a.w + p.w;
  ((float4*)(x + (size_t)i * E_DIM))[threadIdx.x] = o;
}

// ---------------- layernorm: f32 in -> bf16 out ---------------------------
__global__ __launch_bounds__(256) void ln_k(const float* __restrict__ x,
                                            const float* __restrict__ s,
                                            const float* __restrict__ b,
                                            unsigned short* __restrict__ out) {
  const int row = blockIdx.x, tid = threadIdx.x;
  const float4 v = ((const float4*)(x + (size_t)row * E_DIM))[tid];
  float sum = v.x + v.y + v.z + v.w;
  float sq  = v.x * v.x + v.y * v.y + v.z * v.z + v.w * v.w;
  #pragma unroll
  for (int off = 32; off; off >>= 1) {
    sum += __shfl_down(sum, off);
    sq  += __shfl_down(sq, off);
  }
  __shared__ float sm[10];
  const int wave = tid >> 6, lane = tid & 63;
  if (lane == 0) { sm[wave] = sum; sm[4 + wave] = sq; }
  __syncthreads();
  if (tid == 0) {
    const float ts = sm[0] + sm[1] + sm[2] + sm[3];
    const float tq = sm[4] + sm[5] + sm[6] + sm[7];
    const float mean = ts * (1.0f / E_DIM);
    const float var = tq * (1.0f / E_DIM) - mean * mean;
    sm[8] = mean;
    sm[9] = 1.0f / sqrtf(var + 1e-5f);
  }
  __syncthreads();
  const float mean = sm[8], inv = sm[9];
  const float4 sv = ((const float4*)s)[tid];
  const float4 bv = ((const float4*)b)[tid];
  ushort4 o;
  o.x = f2bf((v.x - mean) * inv * sv.x + bv.x);
  o.y = f2bf((v.y - mean) * inv * sv.y + bv.y);
  o.z = f2bf((v.z - mean) * inv * sv.z + bv.z);
  o.w = f2bf((v.w - mean) * inv * sv.w + bv.w);
  *(ushort4*)(out + (size_t)row * E_DIM + (tid << 2)) = o;
}

// ------- batched transpose + f32->bf16: WT[n][k] = W[k][n], z = layer -----
__global__ __launch_bounds__(256) void transpose_b(const float* __restrict__ W,
                                                   unsigned short* __restrict__ WT,
                                                   int K, int N,
                                                   size_t Wstride, size_t WTstride) {
  __shared__ float tile[32][33];
  const int z = blockIdx.z;
  W  += (size_t)z * Wstride;
  WT += (size_t)z * WTstride;
  const int n0 = blockIdx.x << 5, k0 = blockIdx.y << 5;
  const int tx = threadIdx.x & 31, ty = threadIdx.x >> 5;
  #pragma unroll
  for (int i = ty; i < 32; i += 8)
    tile[i][tx] = W[(size_t)(k0 + i) * N + n0 + tx];
  __syncthreads();
  #pragma unroll
  for (int i = ty; i < 32; i += 8)
    WT[(size_t)(n0 + i) * K + k0 + tx] = f2bf(tile[tx][i]);
}

// ---------------- layer GEMM (R4 structure): dbuf BK=64, 1 barrier/K-tile -
template<int BM, bool RELU, bool BIAS, bool RES, bool OBF16>
__global__ __launch_bounds__(256) void gemm_k(const unsigned short* __restrict__ A,
                                              const unsigned short* __restrict__ WT,
                                              const float* __restrict__ bias,
                                              const float* __restrict__ res,
                                              void* __restrict__ Cout,
                                              int ldc, int K) {
  constexpr int BN = 128;
  constexpr int BK = 64;                    // 128 B rows = 8 slots of 16 B
  constexpr int MF = BM / 32;
  constexpr int AJ = (BM * BK * 2 / 1024) / 4;
  constexpr int BJ = (BN * BK * 2 / 1024) / 4;
  __shared__ __align__(16) unsigned short As[2][BM][BK];
  __shared__ __align__(16) unsigned short Bs[2][BN][BK];
  const int tid = threadIdx.x;
  const int row0 = blockIdx.x * BM, col0 = blockIdx.y * BN;
  const int wave = tid >> 6, lane = tid & 63;
  const int wm = (wave >> 1) * (BM / 2), wn = (wave & 1) * 64;
  const int lr = lane & 15, lg = lane >> 4;
  const int ric = lane >> 3, sslot = lane & 7;

  auto stage = [&](int buf, int k0) {
    #pragma unroll
    for (int j = 0; j < AJ; ++j) {
      const int c = wave + 4 * j;
      const int row = c * 8 + ric;
      const int sp = sslot ^ (row & 7);
      gload_lds16(A + (size_t)(row0 + row) * K + k0 + sp * 8,
                  (char*)&As[buf][0][0] + c * 1024);
    }
    #pragma unroll
    for (int j = 0; j < BJ; ++j) {
      const int c = wave + 4 * j;
      const int row = c * 8 + ric;
      const int sp = sslot ^ (row & 7);
      gload_lds16(WT + (size_t)(col0 + row) * K + k0 + sp * 8,
                  (char*)&Bs[buf][0][0] + c * 1024);
    }
  };

  f32x4 acc[MF][4] = {};
  const int nt = K / BK;
  stage(0, 0);
  __syncthreads();
  for (int t = 0; t < nt; ++t) {
    const int cur = t & 1;
    if (t + 1 < nt) stage(cur ^ 1, (t + 1) * BK);
    #pragma unroll
    for (int ks = 0; ks < 2; ++ks) {
      bf16x8 af[MF], bfr[4];
      #pragma unroll
      for (int m = 0; m < MF; ++m) {
        const int r = wm + m * 16 + lr;
        const int s = (ks * 4 + lg) ^ (r & 7);
        af[m] = *(const bf16x8*)((const char*)&As[cur][0][0] + r * 128 + s * 16);
      }
      #pragma unroll
      for (int n = 0; n < 4; ++n) {
        const int r = wn + n * 16 + lr;
        const int s = (ks * 4 + lg) ^ (r & 7);
        bfr[n] = *(const bf16x8*)((const char*)&Bs[cur][0][0] + r * 128 + s * 16);
      }
      #pragma unroll
      for (int m = 0; m < MF; ++m)
        #pragma unroll
        for (int n = 0; n < 4; ++n)
          acc[m][n] = __builtin_amdgcn_mfma_f32_16x16x32_bf16(af[m], bfr[n], acc[m][n], 0, 0, 0);
    }
    __syncthreads();
  }
  float* Cf = (float*)Cout;
  unsigned short* Cb = (unsigned short*)Cout;
  #pragma unroll
  for (int m = 0; m < MF; ++m) {
    #pragma unroll
    for (int n = 0; n < 4; ++n) {
      const int col = col0 + wn + (n << 4) + lr;
      const float bv = BIAS ? bias[col] : 0.0f;
      #pragma unroll
      for (int r = 0; r < 4; ++r) {
        const int row = row0 + wm + (m << 4) + (lg << 2) + r;
        float val = acc[m][n][r] + bv;
        if (RELU) val = fmaxf(val, 0.0f);
        if (RES)  val += res[(size_t)row * ldc + col];
        if (OBF16) Cb[(size_t)row * ldc + col] = f2bf(val);
        else       Cf[(size_t)row * ldc + col] = val;
      }
    }
  }
}

// ---------------- head GEMM: 8-phase 256x256, 8 waves, counted vmcnt ------
// Per-wave 128x64 output as 2x2 quadrants; m-quadrant<->A-half,
// n-quadrant<->B-half. Per K-tile 4 phases, quadrant order
// (0,0),(0,1),(1,1),(1,0); halves read: A0{p0,p1(reg)}, B0{p0,p3},
// B1{p1,p2(reg)}, A1{p2,p3(reg)}. Staging calendar (race-free, see notes):
// ph0: B0,A1(t+1) -> buf^1 ; ph2: A0(t+2) -> buf ; ph3: B1(t+2) -> buf,
// then vmcnt(4) (drains all of t+1; 2 halves stay in flight).
#define LOAD_AF(HALF)                                                         \
  _Pragma("unroll")                                                           \
  for (int mf = 0; mf < 4; ++mf) {                                            \
    const int rr = wm * 64 + mf * 16 + lr;                                    \
    _Pragma("unroll")                                                         \
    for (int ks = 0; ks < 2; ++ks)                                            \
      af[mf][ks] = *(const bf16x8*)&As[buf][HALF][rr]                         \
          [(((ks << 2) + lgp) ^ (rr & 7)) << 3];                              \
  }
#define LOAD_BF(HALF)                                                         \
  _Pragma("unroll")                                                           \
  for (int nf = 0; nf < 2; ++nf) {                                            \
    const int rr = wn * 32 + nf * 16 + lr;                                    \
    _Pragma("unroll")                                                         \
    for (int ks = 0; ks < 2; ++ks)                                            \
      bfq[nf][ks] = *(const bf16x8*)&Bs[buf][HALF][rr]                        \
          [(((ks << 2) + lgp) ^ (rr & 7)) << 3];                              \
  }
#define MFMA_Q(MH, NH)                                                        \
  __builtin_amdgcn_s_setprio(1);                                              \
  _Pragma("unroll")                                                           \
  for (int mf = 0; mf < 4; ++mf)                                              \
    _Pragma("unroll")                                                         \
    for (int nf = 0; nf < 2; ++nf) {                                          \
      acc[MH][NH][mf][nf] = __builtin_amdgcn_mfma_f32_16x16x32_bf16(          \
          af[mf][0], bfq[nf][0], acc[MH][NH][mf][nf], 0, 0, 0);               \
      acc[MH][NH][mf][nf] = __builtin_amdgcn_mfma_f32_16x16x32_bf16(          \
          af[mf][1], bfq[nf][1], acc[MH][NH][mf][nf], 0, 0, 0);               \
    }                                                                         \
  __builtin_amdgcn_s_setprio(0);

__global__ __launch_bounds__(512) void gemm8_k(
    const unsigned short* __restrict__ A, const unsigned short* __restrict__ WT,
    const float* __restrict__ bias, float* __restrict__ C,
    int ldc, int K, int mgrid) {
  constexpr int BK = 64;
  __shared__ __align__(16) unsigned short As[2][2][128][64];
  __shared__ __align__(16) unsigned short Bs[2][2][128][64];
  const int tid = threadIdx.x;
  const int wave = tid >> 6, lane = tid & 63;
  const int wm = wave >> 2, wn = wave & 3;
  const int lr = lane & 15, lgp = lane >> 4;
  // bijective XCD swizzle (m204): contiguous logical range per XCD
  const int nwg = gridDim.x;
  const int q = nwg >> 3, r = nwg & 7;
  const int xcd = blockIdx.x & 7;
  const int lgid = (xcd < r ? xcd * (q + 1) : r * (q + 1) + (xcd - r) * q)
                   + (blockIdx.x >> 3);
  const int row0 = (lgid % mgrid) * 256, col0 = (lgid / mgrid) * 256;
  const int srow = lane >> 3, sslot = lane & 7;

  auto stA = [&](int buf, int half, int k0) {
    #pragma unroll
    for (int j = 0; j < 2; ++j) {
      const int row = j * 64 + wave * 8 + srow;
      const int sp = sslot ^ (row & 7);
      gload_lds16(A + (size_t)(row0 + half * 128 + row) * K + k0 + sp * 8,
                  (char*)&As[buf][half][0][0] + j * 8192 + wave * 1024);
    }
  };
  auto stB = [&](int buf, int half, int k0) {
    #pragma unroll
    for (int j = 0; j < 2; ++j) {
      const int row = j * 64 + wave * 8 + srow;
      const int sp = sslot ^ (row & 7);
      gload_lds16(WT + (size_t)(col0 + half * 128 + row) * K + k0 + sp * 8,
                  (char*)&Bs[buf][half][0][0] + j * 8192 + wave * 1024);
    }
  };

  f32x4 acc[2][2][4][2] = {};
  bf16x8 af[4][2], bfq[2][2];
  const int nt = K / BK;

  // prologue: A0(0),B1(0),B0(0),A1(0),A0(1),B1(1); drain tile0, keep 2 halves
  stA(0, 0, 0); stB(0, 1, 0); stB(0, 0, 0); stA(0, 1, 0);
  if (nt > 1) {
    stA(1, 0, BK); stB(1, 1, BK);
    asm volatile("s_waitcnt vmcnt(4)" ::: "memory");
  } else {
    asm volatile("s_waitcnt vmcnt(0)" ::: "memory");
  }
  __builtin_amdgcn_s_barrier();

  for (int t = 0; t < nt; ++t) {
    const int buf = t & 1, nbuf = buf ^ 1;
    const int k0 = t * BK;
    // ---- phase 0: quadrant (0,0); stage B0(t+1), A1(t+1)
    LOAD_AF(0)
    LOAD_BF(0)
    if (t + 1 < nt) { stB(nbuf, 0, k0 + BK); stA(nbuf, 1, k0 + BK); }
    __builtin_amdgcn_s_barrier();
    MFMA_Q(0, 0)
    __builtin_amdgcn_s_barrier();
    // ---- phase 1: quadrant (0,1); A-frags reused
    LOAD_BF(1)
    __builtin_amdgcn_s_barrier();
    MFMA_Q(0, 1)
    __builtin_amdgcn_s_barrier();
    // ---- phase 2: quadrant (1,1); B-frags reused; stage A0(t+2)
    LOAD_AF(1)
    if (t + 2 < nt) stA(buf, 0, k0 + 2 * BK);
    __builtin_amdgcn_s_barrier();
    MFMA_Q(1, 1)
    __builtin_amdgcn_s_barrier();
    // ---- phase 3: quadrant (1,0); re-read B0; stage B1(t+2); counted vmcnt
    LOAD_BF(0)
    if (t + 2 < nt) stB(buf, 1, k0 + 2 * BK);
    __builtin_amdgcn_s_barrier();
    MFMA_Q(1, 0)
    if (t + 1 < nt) {
      if (t + 2 < nt) asm volatile("s_waitcnt vmcnt(4)" ::: "memory");
      else            asm volatile("s_waitcnt vmcnt(0)" ::: "memory");
    }
    __builtin_amdgcn_s_barrier();
  }

  #pragma unroll
  for (int mh = 0; mh < 2; ++mh)
    #pragma unroll
    for (int nh = 0; nh < 2; ++nh)
      #pragma unroll
      for (int mf = 0; mf < 4; ++mf)
        #pragma unroll
        for (int nf = 0; nf < 2; ++nf) {
          const int col = col0 + nh * 128 + wn * 32 + nf * 16 + lr;
          const float bv = bias[col];
          #pragma unroll
          for (int rr = 0; rr < 4; ++rr) {
            const int row = row0 + mh * 128 + wm * 64 + mf * 16 + lgp * 4 + rr;
            C[(size_t)row * ldc + col] = acc[mh][nh][mf][nf][rr] + bv;
          }
        }
}

// ---------------- MFMA flash attention ------------------------------------
#define QBLK 64
#define KBLK 64
__global__ __launch_bounds__(256) void fattn_k(const unsigned short* __restrict__ qkv,
                                               unsigned short* __restrict__ ob) {
  const int qt = blockIdx.x, h = blockIdx.y, b = blockIdx.z;
  const int tid = threadIdx.x;
  const int wave = tid >> 6, lane = tid & 63;
  const int lr = lane & 15, lg = lane >> 4;
  const int q0 = qt * QBLK;

  __shared__ __align__(16) unsigned short Qs[QBLK][72];
  __shared__ __align__(16) unsigned short Ks[KBLK][72];
  __shared__ __align__(16) unsigned short Vt[D_HEAD][72];
  __shared__ __align__(16) unsigned short Ps[QBLK][72];

  const size_t base = (size_t)b * T_SEQ * 3072 + (size_t)h * 64;
  const int srow = tid >> 3, scol = (tid & 7) << 3;

  #pragma unroll
  for (int it = 0; it < 2; ++it) {
    const int row = srow + it * 32;
    *(uint4*)&Qs[row][scol] =
        *(const uint4*)(qkv + base + (size_t)(q0 + row) * 3072 + scol);
  }
  __syncthreads();
  bf16x8 qf[2];
  #pragma unroll
  for (int ks = 0; ks < 2; ++ks)
    qf[ks] = *(const bf16x8*)&Qs[wave * 16 + lr][ks * 32 + lg * 8];

  f32x4 acc_o[4] = {};
  float mrow[4], lrow[4];
  #pragma unroll
  for (int r = 0; r < 4; ++r) { mrow[r] = -3.0e38f; lrow[r] = 0.f; }

  const int ntile = qt + 1;
  for (int kt = 0; kt < ntile; ++kt) {
    const int s0 = kt * KBLK;
    __syncthreads();
    #pragma unroll
    for (int it = 0; it < 2; ++it) {
      const int row = srow + it * 32;
      *(uint4*)&Ks[row][scol] =
          *(const uint4*)(qkv + base + 1024 + (size_t)(s0 + row) * 3072 + scol);
      uint4 v4 = *(const uint4*)(qkv + base + 2048 + (size_t)(s0 + row) * 3072 + scol);
      const unsigned short* vs = (const unsigned short*)&v4;
      #pragma unroll
      for (int j = 0; j < 8; ++j) Vt[scol + j][row] = vs[j];
    }
    __syncthreads();

    f32x4 sacc[4] = {};
    #pragma unroll
    for (int ks = 0; ks < 2; ++ks) {
      #pragma unroll
      for (int nf = 0; nf < 4; ++nf) {
        bf16x8 kf = *(const bf16x8*)&Ks[nf * 16 + lr][ks * 32 + lg * 8];
        sacc[nf] = __builtin_amdgcn_mfma_f32_16x16x32_bf16(qf[ks], kf, sacc[nf], 0, 0, 0);
      }
    }
    float sv[4][4];
    #pragma unroll
    for (int nf = 0; nf < 4; ++nf)
      #pragma unroll
      for (int r = 0; r < 4; ++r) sv[nf][r] = sacc[nf][r] * 0.125f;
    if (kt == ntile - 1) {
      #pragma unroll
      for (int nf = 0; nf < 4; ++nf) {
        const int s = s0 + nf * 16 + lr;
        #pragma unroll
        for (int r = 0; r < 4; ++r) {
          const int q = q0 + wave * 16 + lg * 4 + r;
          if (s > q) sv[nf][r] = -3.0e38f;
        }
      }
    }
    float p[4][4];
    #pragma unroll
    for (int r = 0; r < 4; ++r) {
      float mx = fmaxf(fmaxf(sv[0][r], sv[1][r]), fmaxf(sv[2][r], sv[3][r]));
      #pragma unroll
      for (int off = 1; off < 16; off <<= 1) mx = fmaxf(mx, __shfl_xor(mx, off));
      const float mnew = fmaxf(mrow[r], mx);
      const float alpha = __expf(mrow[r] - mnew);
      mrow[r] = mnew;
      float sum = 0.f;
      #pragma unroll
      for (int nf = 0; nf < 4; ++nf) {
        p[nf][r] = __expf(sv[nf][r] - mnew);
        sum += p[nf][r];
      }
      #pragma unroll
      for (int off = 1; off < 16; off <<= 1) sum += __shfl_xor(sum, off);
      lrow[r] = lrow[r] * alpha + sum;
      #pragma unroll
      for (int df = 0; df < 4; ++df) acc_o[df][r] *= alpha;
    }
    #pragma unroll
    for (int nf = 0; nf < 4; ++nf)
      #pragma unroll
      for (int r = 0; r < 4; ++r)
        Ps[wave * 16 + lg * 4 + r][nf * 16 + lr] = f2bf(p[nf][r]);
    __syncthreads();
    #pragma unroll
    for (int ks = 0; ks < 2; ++ks) {
      bf16x8 pa = *(const bf16x8*)&Ps[wave * 16 + lr][ks * 32 + lg * 8];
      #pragma unroll
      for (int df = 0; df < 4; ++df) {
        bf16x8 vf = *(const bf16x8*)&Vt[df * 16 + lr][ks * 32 + lg * 8];
        acc_o[df] = __builtin_amdgcn_mfma_f32_16x16x32_bf16(pa, vf, acc_o[df], 0, 0, 0);
      }
    }
  }
  #pragma unroll
  for (int r = 0; r < 4; ++r) {
    const float inv = 1.0f / lrow[r];
    const int row = q0 + wave * 16 + lg * 4 + r;
    #pragma unroll
    for (int df = 0; df < 4; ++df)
      ob[((size_t)b * T_SEQ + row) * E_DIM + h * 64 + df * 16 + lr] =
          f2bf(acc_o[df][r] * inv);
  }
}

extern "C" void kernel_launch(void* const* d_in, const int* in_sizes, int n_in,
                              void* d_out, int out_size, void* d_ws, size_t ws_size,
                              hipStream_t stream) {
  (void)in_sizes; (void)n_in; (void)out_size; (void)ws_size;
  const int*   idx    = (const int*)d_in[0];
  const float* tok_w  = (const float*)d_in[1];
  const float* pos    = (const float*)d_in[2];
  const float* ln1_s  = (const float*)d_in[3];
  const float* ln1_b  = (const float*)d_in[4];
  const float* wq     = (const float*)d_in[5];
  const float* wk     = (const float*)d_in[6];
  const float* wv     = (const float*)d_in[7];
  const float* wo     = (const float*)d_in[8];
  const float* bo     = (const float*)d_in[9];
  const float* ln2_s  = (const float*)d_in[10];
  const float* ln2_b  = (const float*)d_in[11];
  const float* w1     = (const float*)d_in[12];
  const float* b1     = (const float*)d_in[13];
  const float* w2     = (const float*)d_in[14];
  const float* b2     = (const float*)d_in[15];
  const float* lnf_s  = (const float*)d_in[16];
  const float* lnf_b  = (const float*)d_in[17];
  const float* head_w = (const float*)d_in[18];
  const float* head_b = (const float*)d_in[19];
  float* out = (float*)d_out;

  char* p = (char*)d_ws;
  float* x            = (float*)p;          p += (size_t)M_ROWS * E_DIM * 4;
  unsigned short* qkvb= (unsigned short*)p; p += (size_t)M_ROWS * 3072 * 2;
  unsigned short* h   = (unsigned short*)p; p += (size_t)M_ROWS * E_DIM * 2;
  unsigned short* obuf= (unsigned short*)p; p += (size_t)M_ROWS * E_DIM * 2;
  unsigned short* ff  = (unsigned short*)p; p += (size_t)M_ROWS * FF_DIM * 2;
  unsigned short* wtqkv=(unsigned short*)p; p += (size_t)L_NUM * 3072 * E_DIM * 2;
  unsigned short* wto = (unsigned short*)p; p += (size_t)L_NUM * E_DIM * E_DIM * 2;
  unsigned short* wt1 = (unsigned short*)p; p += (size_t)L_NUM * FF_DIM * E_DIM * 2;
  unsigned short* wt2 = (unsigned short*)p; p += (size_t)L_NUM * E_DIM * FF_DIM * 2;
  unsigned short* wth = (unsigned short*)p; p += (size_t)32000 * E_DIM * 2;

  // ---- all weight transposes up front (batched over layers) ----
  transpose_b<<<dim3(32, 32, L_NUM), 256, 0, stream>>>(
      wq, wtqkv,           E_DIM, E_DIM, (size_t)E_DIM * E_DIM, (size_t)3072 * E_DIM);
  transpose_b<<<dim3(32, 32, L_NUM), 256, 0, stream>>>(
      wk, wtqkv + 1048576, E_DIM, E_DIM, (size_t)E_DIM * E_DIM, (size_t)3072 * E_DIM);
  transpose_b<<<dim3(32, 32, L_NUM), 256, 0, stream>>>(
      wv, wtqkv + 2097152, E_DIM, E_DIM, (size_t)E_DIM * E_DIM, (size_t)3072 * E_DIM);
  transpose_b<<<dim3(32, 32, L_NUM), 256, 0, stream>>>(
      wo, wto, E_DIM, E_DIM, (size_t)E_DIM * E_DIM, (size_t)E_DIM * E_DIM);
  transpose_b<<<dim3(128, 32, L_NUM), 256, 0, stream>>>(
      w1, wt1, E_DIM, FF_DIM, (size_t)E_DIM * FF_DIM, (size_t)FF_DIM * E_DIM);
  transpose_b<<<dim3(32, 128, L_NUM), 256, 0, stream>>>(
      w2, wt2, FF_DIM, E_DIM, (size_t)E_DIM * FF_DIM, (size_t)E_DIM * FF_DIM);
  transpose_b<<<dim3(1000, 32, 1), 256, 0, stream>>>(
      head_w, wth, E_DIM, 32000, 0, 0);

  embed_k<<<M_ROWS, 256, 0, stream>>>(idx, tok_w, pos, x);

  for (int l = 0; l < L_NUM; ++l) {
    // ---- LN1 ----
    ln_k<<<M_ROWS, 256, 0, stream>>>(x, ln1_s + l * E_DIM, ln1_b + l * E_DIM, h);
    // ---- QKV (fused, N = 3072, bf16 out): 128x128, m-fastest ----
    gemm_k<128,false,false,false,true><<<dim3(16, 24), 256, 0, stream>>>(
        h, wtqkv + (size_t)l * 3072 * E_DIM, nullptr, nullptr, qkvb, 3072, E_DIM);
    // ---- flash attention ----
    fattn_k<<<dim3(T_SEQ / QBLK, H_NUM, B_NUM), 256, 0, stream>>>(qkvb, obuf);
    // ---- out-proj + bias + residual into x: 64x128 ----
    gemm_k<64,false,true,true,false><<<dim3(32, 8), 256, 0, stream>>>(
        obuf, wto + (size_t)l * E_DIM * E_DIM, bo + l * E_DIM, x, x, E_DIM, E_DIM);
    // ---- LN2 ----
    ln_k<<<M_ROWS, 256, 0, stream>>>(x, ln2_s + l * E_DIM, ln2_b + l * E_DIM, h);
    // ---- MLP up + ReLU (bf16 out): 128x128 ----
    gemm_k<128,true,true,false,true><<<dim3(16, 32), 256, 0, stream>>>(
        h, wt1 + (size_t)l * FF_DIM * E_DIM, b1 + l * FF_DIM, nullptr, ff, FF_DIM, E_DIM);
    // ---- MLP down + bias + residual into x: 64x128, K=4096 ----
    gemm_k<64,false,true,true,false><<<dim3(32, 8), 256, 0, stream>>>(
        ff, wt2 + (size_t)l * E_DIM * FF_DIM, b2 + l * E_DIM, x, x, E_DIM, FF_DIM);
  }

  // ---- final LN + head: 8-phase 256x256, 1000 blocks, XCD-swizzled ----
  ln_k<<<M_ROWS, 256, 0, stream>>>(x, lnf_s, lnf_b, h);
  gemm8_k<<<1000, 512, 0, stream>>>(h, wth, head_b, out, 32000, E_DIM, 8);
}